// Round 1
// baseline (164.366 us; speedup 1.0000x reference)
//
#include <hip/hip_runtime.h>
#include <math.h>

#define NC 16      // components
#define DIM 16
#define LAYERS 6

// ws layout (floats):
//   [0, 4096)    Linv[c][i][j]  (row-major, full 16x16 with zeros above diag)
//   [4096, 4112) cst[c] = -0.5*DIM*log(2pi) - half_logdet[c]
//   [4112, 4208) alpha[l][c] = exp(log_alpha[l][c])

__global__ void prep_kernel(const float* __restrict__ cov,
                            const float* __restrict__ log_alpha,
                            float* __restrict__ ws) {
    __shared__ float A[NC * DIM * 17];   // padded rows: A[c][i][j] at c*272 + i*17 + j
    const int tid = threadIdx.x;         // 256 threads
    for (int t = tid; t < NC * DIM * DIM; t += 256) {
        int c = t >> 8, r = (t >> 4) & 15, j = t & 15;
        A[c * (DIM * 17) + r * 17 + j] = cov[t];
    }
    __syncthreads();
    const int c = tid >> 4;
    const int i = tid & 15;
    float* Ac = A + c * (DIM * 17);
    // Parallel right-looking Cholesky: thread (c,i) owns row i of component c.
    for (int k = 0; k < DIM; ++k) {
        if (i == k) Ac[k * 17 + k] = sqrtf(Ac[k * 17 + k]);
        __syncthreads();
        if (i > k) Ac[i * 17 + k] /= Ac[k * 17 + k];
        __syncthreads();
        if (i > k) {
            float lik = Ac[i * 17 + k];
            for (int j = k + 1; j <= i; ++j)
                Ac[i * 17 + j] -= lik * Ac[j * 17 + k];
        }
        __syncthreads();
    }
    // Triangular inversion: thread (c,i) computes column j=i of Linv_c by fwd-substitution.
    {
        const int j = i;
        float x[DIM];
        #pragma unroll
        for (int r = 0; r < DIM; ++r) x[r] = 0.0f;
        x[j] = 1.0f / Ac[j * 17 + j];
        for (int r = j + 1; r < DIM; ++r) {
            float s = 0.0f;
            for (int k = j; k < r; ++k) s += Ac[r * 17 + k] * x[k];
            x[r] = -s / Ac[r * 17 + r];
        }
        for (int r = 0; r < DIM; ++r)
            ws[c * 256 + r * 16 + j] = (r >= j) ? x[r] : 0.0f;
    }
    // cst[c]
    if (tid < NC) {
        float hld = 0.0f;
        const float* Acc = A + tid * (DIM * 17);
        for (int r = 0; r < DIM; ++r) hld += __logf(Acc[r * 17 + r]);
        const float log2pi = 1.8378770664093453f;
        ws[4096 + tid] = -0.5f * (float)DIM * log2pi - hld;
    }
    // alpha = exp(log_alpha)
    if (tid < LAYERS * NC) ws[4112 + tid] = __expf(log_alpha[tid]);
}

__global__ void __launch_bounds__(1024) density_kernel(
    const float* __restrict__ z, const float* __restrict__ z0,
    const float* __restrict__ beta, const float* __restrict__ mean,
    const float* __restrict__ ws, float* __restrict__ out, int N) {
    __shared__ float tile[64 * 17];
    const int lane = threadIdx.x & 63;
    // c is wave-uniform: force into SGPR so all param loads become s_loads.
    const int c = __builtin_amdgcn_readfirstlane(threadIdx.x >> 6);
    int s = blockIdx.x * 64 + lane;
    int sl = s < N ? s : N - 1;          // clamp; only final store is guarded

    float zc[DIM];
    {
        const float4* zp = (const float4*)(z + (size_t)sl * DIM);
        float4 a0 = zp[0], a1 = zp[1], a2 = zp[2], a3 = zp[3];
        zc[0] = a0.x; zc[1] = a0.y; zc[2] = a0.z; zc[3] = a0.w;
        zc[4] = a1.x; zc[5] = a1.y; zc[6] = a1.z; zc[7] = a1.w;
        zc[8] = a2.x; zc[9] = a2.y; zc[10] = a2.z; zc[11] = a2.w;
        zc[12] = a3.x; zc[13] = a3.y; zc[14] = a3.z; zc[15] = a3.w;
    }

    const float* wsA = ws + 4112;   // alpha[l][c]
    const float* cstp = ws + 4096;  // cst[c]
    float slj = 0.0f;

    #pragma unroll
    for (int l = 0; l < LAYERS; ++l) {
        const float* z0r = z0 + ((l * NC + c) * DIM);
        float d[DIM];
        float r2 = 0.0f;
        #pragma unroll
        for (int i = 0; i < DIM; ++i) {
            d[i] = zc[i] - z0r[i];
            r2 = fmaf(d[i], d[i], r2);
        }
        float r = sqrtf(r2);
        float al = wsA[l * NC + c];
        float b  = beta[l * NC + c];
        float h  = __builtin_amdgcn_rcpf(al + r);
        float bh = b * h;
        #pragma unroll
        for (int i = 0; i < DIM; ++i) zc[i] = fmaf(bh, d[i], zc[i]);
        // log_det = 15*log1p(bh) + log1p(bh - b*r*h*h)
        float t2 = fmaf(-(b * r * h), h, bh);
        slj += 15.0f * __logf(1.0f + bh) + __logf(1.0f + t2);
    }

    // q = || Linv_c * (zk - mean_c) ||^2  (triangular matvec, Linv via s_loads)
    const float* Li = ws + c * 256;
    const float* mr = mean + c * DIM;
    float dd[DIM];
    #pragma unroll
    for (int i = 0; i < DIM; ++i) dd[i] = zc[i] - mr[i];
    float q = 0.0f;
    #pragma unroll
    for (int i = 0; i < DIM; ++i) {
        float acc = 0.0f;
        #pragma unroll
        for (int j = 0; j <= i; ++j) acc = fmaf(Li[i * 16 + j], dd[j], acc);
        q = fmaf(acc, acc, q);
    }

    float res = cstp[c] + fmaf(-0.5f, q, slj);
    if (res != res) res = -INFINITY;   // NaN -> -inf (reference semantics)

    // Transpose through LDS so the global store is fully coalesced.
    tile[lane * 17 + c] = res;
    __syncthreads();
    const int t = threadIdx.x;
    const int srow = t >> 4, col = t & 15;
    const int gs = blockIdx.x * 64 + srow;
    if (gs < N) out[(size_t)gs * NC + col] = tile[srow * 17 + col];
}

extern "C" void kernel_launch(void* const* d_in, const int* in_sizes, int n_in,
                              void* d_out, int out_size, void* d_ws, size_t ws_size,
                              hipStream_t stream) {
    const float* z    = (const float*)d_in[0];
    const float* z0   = (const float*)d_in[1];
    const float* la   = (const float*)d_in[2];
    const float* beta = (const float*)d_in[3];
    const float* mean = (const float*)d_in[4];
    const float* cov  = (const float*)d_in[5];
    float* out = (float*)d_out;
    float* ws  = (float*)d_ws;
    const int N = in_sizes[0] / DIM;

    hipLaunchKernelGGL(prep_kernel, dim3(1), dim3(256), 0, stream, cov, la, ws);
    const int nb = (N + 63) / 64;
    hipLaunchKernelGGL(density_kernel, dim3(nb), dim3(1024), 0, stream,
                       z, z0, beta, mean, ws, out, N);
}

// Round 3
// 147.013 us; speedup vs baseline: 1.1180x; 1.1180x over previous
//
#include <hip/hip_runtime.h>
#include <math.h>

#define NC 16
#define DIM 16
#define LAYERS 6

// ws layout (floats)
#define WS_LINV  0      // [NC][DIM][DIM] row-major, 4096
#define WS_MU2   4096   // [NC][DIM] = Linv_c * mean_c, 256
#define WS_CST   4352   // [NC], 16
#define WS_ALPHA 4368   // [L][NC] = exp(log_alpha), 96
#define WS_TOT   4464

// density LDS param block layout (first WS_TOT floats mirror ws)
#define SP_BETA  4464   // [L][NC], 96
#define SP_Z0    4560   // [L][NC][DIM], 1536
#define SP_TOT   6096

__global__ void prep_kernel(const float* __restrict__ cov,
                            const float* __restrict__ log_alpha,
                            const float* __restrict__ mean,
                            float* __restrict__ ws) {
    __shared__ float A[NC * DIM * 17];   // padded: A[c][i][j] at c*272 + i*17 + j
    __shared__ float B[NC * DIM * DIM];  // Linv staged for mu2 matvec
    const int tid = threadIdx.x;         // 256 threads
    for (int t = tid; t < NC * DIM * DIM; t += 256) {
        int c = t >> 8, r = (t >> 4) & 15, j = t & 15;
        A[c * 272 + r * 17 + j] = cov[t];
    }
    __syncthreads();
    const int c = tid >> 4;
    const int i = tid & 15;
    float* Ac = A + c * 272;
    // Parallel right-looking Cholesky: thread (c,i) owns row i.
    for (int k = 0; k < DIM; ++k) {
        if (i == k) Ac[k * 17 + k] = sqrtf(Ac[k * 17 + k]);
        __syncthreads();
        if (i > k) Ac[i * 17 + k] /= Ac[k * 17 + k];
        __syncthreads();
        if (i > k) {
            float lik = Ac[i * 17 + k];
            for (int j2 = k + 1; j2 <= i; ++j2)
                Ac[i * 17 + j2] -= lik * Ac[j2 * 17 + k];
        }
        __syncthreads();
    }
    // Forward substitution for column j=i of Linv — FULLY UNROLLED so x[]
    // stays in VGPRs (runtime-indexed arrays go to scratch => 60+ us kernel).
    const int j = i;
    float x[DIM];
    #pragma unroll
    for (int r = 0; r < DIM; ++r) {
        float s = (r == j) ? 1.0f : 0.0f;   // rows above j stay exactly 0
        #pragma unroll
        for (int k = 0; k < r; ++k) s = fmaf(-Ac[r * 17 + k], x[k], s);
        x[r] = s / Ac[r * 17 + r];
    }
    #pragma unroll
    for (int r = 0; r < DIM; ++r) {
        B[c * 256 + r * 16 + j] = x[r];
        ws[WS_LINV + c * 256 + r * 16 + j] = x[r];
    }
    if (tid < NC) {
        float hld = 0.0f;
        const float* Acc = A + tid * 272;
        #pragma unroll
        for (int r = 0; r < DIM; ++r) hld += __logf(Acc[r * 17 + r]);
        const float log2pi = 1.8378770664093453f;
        ws[WS_CST + tid] = -0.5f * (float)DIM * log2pi - hld;
    }
    if (tid < LAYERS * NC) ws[WS_ALPHA + tid] = __expf(log_alpha[tid]);
    __syncthreads();
    // mu2[c][i] = sum_j Linv[c][i][j] * mean[c][j]
    float m2 = 0.0f;
    #pragma unroll
    for (int jj = 0; jj < DIM; ++jj)
        m2 = fmaf(B[c * 256 + i * 16 + jj], mean[c * DIM + jj], m2);
    ws[WS_MU2 + c * 16 + i] = m2;
}

__global__ void __launch_bounds__(1024, 8) density_kernel(
    const float* __restrict__ z, const float* __restrict__ z0,
    const float* __restrict__ beta, const float* __restrict__ ws,
    float* __restrict__ out, int N) {
    __shared__ float sp[SP_TOT];
    __shared__ float tile[64 * 17];
    const int tid = threadIdx.x;
    // Cooperative staging of ALL params into LDS. NB: SP_TOT (6096) > block
    // size — MUST be a strided loop (Round-2 bug: single predicated store
    // left z0[1024:1536] unstaged -> inf).
    for (int t = tid; t < SP_TOT; t += 1024) {
        float v;
        if (t < WS_TOT)       v = ws[t];
        else if (t < SP_Z0)   v = beta[t - SP_BETA];
        else                  v = z0[t - SP_Z0];
        sp[t] = v;
    }
    __syncthreads();

    const int lane = tid & 63;
    // c is wave-uniform: all param LDS reads are broadcast (conflict-free).
    const int c = __builtin_amdgcn_readfirstlane(tid >> 6);
    const int s = blockIdx.x * 64 + lane;
    const int sl = s < N ? s : N - 1;    // clamp; only final store is guarded

    float zc[DIM];
    {
        const float4* zp = (const float4*)(z + (size_t)sl * DIM);
        float4 a0 = zp[0], a1 = zp[1], a2 = zp[2], a3 = zp[3];
        zc[0] = a0.x; zc[1] = a0.y; zc[2] = a0.z; zc[3] = a0.w;
        zc[4] = a1.x; zc[5] = a1.y; zc[6] = a1.z; zc[7] = a1.w;
        zc[8] = a2.x; zc[9] = a2.y; zc[10] = a2.z; zc[11] = a2.w;
        zc[12] = a3.x; zc[13] = a3.y; zc[14] = a3.z; zc[15] = a3.w;
    }

    float slj = 0.0f;
    #pragma unroll
    for (int l = 0; l < LAYERS; ++l) {
        const float4* z0r = (const float4*)(sp + SP_Z0 + (l * NC + c) * DIM);
        float4 b0 = z0r[0], b1 = z0r[1], b2 = z0r[2], b3 = z0r[3];
        float z0v[DIM];
        z0v[0] = b0.x; z0v[1] = b0.y; z0v[2] = b0.z; z0v[3] = b0.w;
        z0v[4] = b1.x; z0v[5] = b1.y; z0v[6] = b1.z; z0v[7] = b1.w;
        z0v[8] = b2.x; z0v[9] = b2.y; z0v[10] = b2.z; z0v[11] = b2.w;
        z0v[12] = b3.x; z0v[13] = b3.y; z0v[14] = b3.z; z0v[15] = b3.w;
        float d[DIM];
        float r2 = 0.0f;
        #pragma unroll
        for (int i = 0; i < DIM; ++i) {
            d[i] = zc[i] - z0v[i];
            r2 = fmaf(d[i], d[i], r2);
        }
        float r = sqrtf(r2);
        float al = sp[WS_ALPHA + l * NC + c];
        float b  = sp[SP_BETA + l * NC + c];
        float h  = __builtin_amdgcn_rcpf(al + r);
        float bh = b * h;
        #pragma unroll
        for (int i = 0; i < DIM; ++i) zc[i] = fmaf(bh, d[i], zc[i]);
        float t2 = fmaf(-(b * r * h), h, bh);
        slj += 15.0f * __logf(1.0f + bh) + __logf(1.0f + t2);
    }

    // q = || Linv_c*zk - mu2_c ||^2 (triangular matvec, broadcast LDS reads)
    const float* Li = sp + WS_LINV + c * 256;
    const float* m2 = sp + WS_MU2 + c * 16;
    float q = 0.0f;
    #pragma unroll
    for (int i = 0; i < DIM; ++i) {
        float acc = -m2[i];
        #pragma unroll
        for (int j = 0; j <= i; ++j) acc = fmaf(Li[i * 16 + j], zc[j], acc);
        q = fmaf(acc, acc, q);
    }

    float res = sp[WS_CST + c] + fmaf(-0.5f, q, slj);
    if (res != res) res = -INFINITY;     // NaN -> -inf (reference semantics)

    // Transpose through LDS so the global store is fully coalesced.
    tile[lane * 17 + c] = res;
    __syncthreads();
    const int srow = tid >> 4, col = tid & 15;
    const int gs = blockIdx.x * 64 + srow;
    if (gs < N) out[(size_t)gs * NC + col] = tile[srow * 17 + col];
}

extern "C" void kernel_launch(void* const* d_in, const int* in_sizes, int n_in,
                              void* d_out, int out_size, void* d_ws, size_t ws_size,
                              hipStream_t stream) {
    const float* z    = (const float*)d_in[0];
    const float* z0   = (const float*)d_in[1];
    const float* la   = (const float*)d_in[2];
    const float* beta = (const float*)d_in[3];
    const float* mean = (const float*)d_in[4];
    const float* cov  = (const float*)d_in[5];
    float* out = (float*)d_out;
    float* ws  = (float*)d_ws;
    const int N = in_sizes[0] / DIM;

    hipLaunchKernelGGL(prep_kernel, dim3(1), dim3(256), 0, stream, cov, la, mean, ws);
    const int nb = (N + 63) / 64;
    hipLaunchKernelGGL(density_kernel, dim3(nb), dim3(1024), 0, stream,
                       z, z0, beta, ws, out, N);
}

// Round 4
// 143.459 us; speedup vs baseline: 1.1457x; 1.0248x over previous
//
#include <hip/hip_runtime.h>
#include <math.h>

#define NC 16
#define DIM 16
#define LAYERS 6

// ws layout (floats)
#define WS_LINV  0      // [NC][DIM][DIM] row-major, 4096
#define WS_MU2   4096   // [NC][DIM] = Linv_c * mean_c, 256
#define WS_CST   4352   // [NC], 16
#define WS_ALPHA 4368   // [L][NC] = exp(log_alpha), 96
#define WS_TOT   4464

__global__ void prep_kernel(const float* __restrict__ cov,
                            const float* __restrict__ log_alpha,
                            const float* __restrict__ mean,
                            float* __restrict__ ws) {
    __shared__ float A[NC * DIM * 17];   // padded: A[c][i][j] at c*272 + i*17 + j
    __shared__ float B[NC * DIM * DIM];  // Linv staged for mu2 matvec
    const int tid = threadIdx.x;         // 256 threads
    for (int t = tid; t < NC * DIM * DIM; t += 256) {
        int c = t >> 8, r = (t >> 4) & 15, j = t & 15;
        A[c * 272 + r * 17 + j] = cov[t];
    }
    __syncthreads();
    const int c = tid >> 4;
    const int i = tid & 15;
    float* Ac = A + c * 272;
    // Parallel right-looking Cholesky: thread (c,i) owns row i.
    for (int k = 0; k < DIM; ++k) {
        if (i == k) Ac[k * 17 + k] = sqrtf(Ac[k * 17 + k]);
        __syncthreads();
        if (i > k) Ac[i * 17 + k] /= Ac[k * 17 + k];
        __syncthreads();
        if (i > k) {
            float lik = Ac[i * 17 + k];
            for (int j2 = k + 1; j2 <= i; ++j2)
                Ac[i * 17 + j2] -= lik * Ac[j2 * 17 + k];
        }
        __syncthreads();
    }
    // Forward substitution for column j=i of Linv — FULLY UNROLLED so x[]
    // stays in VGPRs (runtime-indexed arrays go to scratch).
    const int j = i;
    float x[DIM];
    #pragma unroll
    for (int r = 0; r < DIM; ++r) {
        float s = (r == j) ? 1.0f : 0.0f;   // rows above j stay exactly 0
        #pragma unroll
        for (int k = 0; k < r; ++k) s = fmaf(-Ac[r * 17 + k], x[k], s);
        x[r] = s / Ac[r * 17 + r];
    }
    #pragma unroll
    for (int r = 0; r < DIM; ++r) {
        B[c * 256 + r * 16 + j] = x[r];
        ws[WS_LINV + c * 256 + r * 16 + j] = x[r];
    }
    if (tid < NC) {
        float hld = 0.0f;
        const float* Acc = A + tid * 272;
        #pragma unroll
        for (int r = 0; r < DIM; ++r) hld += __logf(Acc[r * 17 + r]);
        const float log2pi = 1.8378770664093453f;
        ws[WS_CST + tid] = -0.5f * (float)DIM * log2pi - hld;
    }
    if (tid < LAYERS * NC) ws[WS_ALPHA + tid] = __expf(log_alpha[tid]);
    __syncthreads();
    // mu2[c][i] = sum_j Linv[c][i][j] * mean[c][j]
    float m2 = 0.0f;
    #pragma unroll
    for (int jj = 0; jj < DIM; ++jj)
        m2 = fmaf(B[c * 256 + i * 16 + jj], mean[c * DIM + jj], m2);
    ws[WS_MU2 + c * 16 + i] = m2;
}

// Params are read straight from global with wave-uniform addresses: the
// compiler proves uniformity (c comes from readfirstlane) and emits
// s_load_dwordx4/x16 on the scalar pipe; SGPR operands then embed directly
// into v_fmac_f32 at zero VALU cost. No param LDS on purpose — Round 3's
// LDS staging + (1024,8) 64-VGPR cap caused scratch spills (WRITE_SIZE
// 12.5 -> 21.8 MB) and a 64 -> 71 us regression.
__global__ void __launch_bounds__(1024, 4) density_kernel(
    const float* __restrict__ z, const float* __restrict__ z0,
    const float* __restrict__ beta, const float* __restrict__ ws,
    float* __restrict__ out, int N) {
    __shared__ float tile[64 * 17];
    const int tid = threadIdx.x;
    const int lane = tid & 63;
    // c is wave-uniform: force into SGPR so all param loads become s_loads.
    const int c = __builtin_amdgcn_readfirstlane(tid >> 6);
    const int s = blockIdx.x * 64 + lane;
    const int sl = s < N ? s : N - 1;    // clamp; only final store is guarded

    float zc[DIM];
    {
        const float4* zp = (const float4*)(z + (size_t)sl * DIM);
        float4 a0 = zp[0], a1 = zp[1], a2 = zp[2], a3 = zp[3];
        zc[0] = a0.x; zc[1] = a0.y; zc[2] = a0.z; zc[3] = a0.w;
        zc[4] = a1.x; zc[5] = a1.y; zc[6] = a1.z; zc[7] = a1.w;
        zc[8] = a2.x; zc[9] = a2.y; zc[10] = a2.z; zc[11] = a2.w;
        zc[12] = a3.x; zc[13] = a3.y; zc[14] = a3.z; zc[15] = a3.w;
    }

    float slj = 0.0f;
    #pragma unroll
    for (int l = 0; l < LAYERS; ++l) {
        const float* z0r = z0 + (l * NC + c) * DIM;   // uniform -> s_load
        float d[DIM];
        float r2 = 0.0f;
        #pragma unroll
        for (int i = 0; i < DIM; ++i) {
            d[i] = zc[i] - z0r[i];
            r2 = fmaf(d[i], d[i], r2);
        }
        float r = sqrtf(r2);
        float al = ws[WS_ALPHA + l * NC + c];          // uniform -> s_load
        float b  = beta[l * NC + c];                   // uniform -> s_load
        float h  = __builtin_amdgcn_rcpf(al + r);
        float bh = b * h;
        #pragma unroll
        for (int i = 0; i < DIM; ++i) zc[i] = fmaf(bh, d[i], zc[i]);
        float t2 = fmaf(-(b * r * h), h, bh);
        slj += 15.0f * __logf(1.0f + bh) + __logf(1.0f + t2);
    }

    // q = || Linv_c*zk - mu2_c ||^2 (triangular matvec, SGPR operands)
    const float* Li = ws + WS_LINV + c * 256;
    const float* m2 = ws + WS_MU2 + c * 16;
    float q = 0.0f;
    #pragma unroll
    for (int i = 0; i < DIM; ++i) {
        float acc = -m2[i];
        #pragma unroll
        for (int j = 0; j <= i; ++j) acc = fmaf(Li[i * 16 + j], zc[j], acc);
        q = fmaf(acc, acc, q);
    }

    float res = ws[WS_CST + c] + fmaf(-0.5f, q, slj);
    if (res != res) res = -INFINITY;     // NaN -> -inf (reference semantics)

    // Transpose through LDS so the global store is fully coalesced
    // (stride-17 rows: 2-way bank aliasing only, which is free on gfx950).
    tile[lane * 17 + c] = res;
    __syncthreads();
    const int srow = tid >> 4, col = tid & 15;
    const int gs = blockIdx.x * 64 + srow;
    if (gs < N) out[(size_t)gs * NC + col] = tile[srow * 17 + col];
}

extern "C" void kernel_launch(void* const* d_in, const int* in_sizes, int n_in,
                              void* d_out, int out_size, void* d_ws, size_t ws_size,
                              hipStream_t stream) {
    const float* z    = (const float*)d_in[0];
    const float* z0   = (const float*)d_in[1];
    const float* la   = (const float*)d_in[2];
    const float* beta = (const float*)d_in[3];
    const float* mean = (const float*)d_in[4];
    const float* cov  = (const float*)d_in[5];
    float* out = (float*)d_out;
    float* ws  = (float*)d_ws;
    const int N = in_sizes[0] / DIM;

    hipLaunchKernelGGL(prep_kernel, dim3(1), dim3(256), 0, stream, cov, la, mean, ws);
    const int nb = (N + 63) / 64;
    hipLaunchKernelGGL(density_kernel, dim3(nb), dim3(1024), 0, stream,
                       z, z0, beta, ws, out, N);
}

// Round 5
// 142.087 us; speedup vs baseline: 1.1568x; 1.0097x over previous
//
#include <hip/hip_runtime.h>
#include <math.h>

#define NC 16
#define DIM 16
#define LAYERS 6

typedef float v2f __attribute__((ext_vector_type(2)));

// ws layout (floats)
#define WS_LINV  0      // [NC][DIM][DIM] row-major, zeros above diag, 4096
#define WS_MU2   4096   // [NC][DIM] = Linv_c * mean_c, 256
#define WS_CST   4352   // [NC], 16
#define WS_ALPHA 4368   // [L][NC] = exp(log_alpha), 96
#define WS_TOT   4464

__global__ void prep_kernel(const float* __restrict__ cov,
                            const float* __restrict__ log_alpha,
                            const float* __restrict__ mean,
                            float* __restrict__ ws) {
    __shared__ float A[NC * DIM * 17];   // padded: A[c][i][j] at c*272 + i*17 + j
    __shared__ float B[NC * DIM * DIM];  // Linv staged for mu2 matvec
    const int tid = threadIdx.x;         // 256 threads
    for (int t = tid; t < NC * DIM * DIM; t += 256) {
        int c = t >> 8, r = (t >> 4) & 15, j = t & 15;
        A[c * 272 + r * 17 + j] = cov[t];
    }
    __syncthreads();
    const int c = tid >> 4;
    const int i = tid & 15;
    float* Ac = A + c * 272;
    // Parallel right-looking Cholesky: thread (c,i) owns row i.
    for (int k = 0; k < DIM; ++k) {
        if (i == k) Ac[k * 17 + k] = sqrtf(Ac[k * 17 + k]);
        __syncthreads();
        if (i > k) Ac[i * 17 + k] /= Ac[k * 17 + k];
        __syncthreads();
        if (i > k) {
            float lik = Ac[i * 17 + k];
            for (int j2 = k + 1; j2 <= i; ++j2)
                Ac[i * 17 + j2] -= lik * Ac[j2 * 17 + k];
        }
        __syncthreads();
    }
    // Forward substitution for column j=i of Linv — FULLY UNROLLED so x[]
    // stays in VGPRs (runtime-indexed arrays go to scratch).
    const int j = i;
    float x[DIM];
    #pragma unroll
    for (int r = 0; r < DIM; ++r) {
        float s = (r == j) ? 1.0f : 0.0f;   // rows above j stay exactly 0
        #pragma unroll
        for (int k = 0; k < r; ++k) s = fmaf(-Ac[r * 17 + k], x[k], s);
        x[r] = s / Ac[r * 17 + r];
    }
    #pragma unroll
    for (int r = 0; r < DIM; ++r) {
        B[c * 256 + r * 16 + j] = x[r];
        ws[WS_LINV + c * 256 + r * 16 + j] = x[r];   // x[r]==0 for r<j
    }
    if (tid < NC) {
        float hld = 0.0f;
        const float* Acc = A + tid * 272;
        #pragma unroll
        for (int r = 0; r < DIM; ++r) hld += __logf(Acc[r * 17 + r]);
        const float log2pi = 1.8378770664093453f;
        ws[WS_CST + tid] = -0.5f * (float)DIM * log2pi - hld;
    }
    if (tid < LAYERS * NC) ws[WS_ALPHA + tid] = __expf(log_alpha[tid]);
    __syncthreads();
    // mu2[c][i] = sum_j Linv[c][i][j] * mean[c][j]
    float m2 = 0.0f;
    #pragma unroll
    for (int jj = 0; jj < DIM; ++jj)
        m2 = fmaf(B[c * 256 + i * 16 + jj], mean[c * DIM + jj], m2);
    ws[WS_MU2 + c * 16 + i] = m2;
}

// Packed-fp32 (VOP3P v_pk_*) version: all 16-wide elementwise loops are
// float2 ext-vectors so each op is one v_pk_fma_f32/v_pk_add_f32.
// Params read via wave-uniform addresses -> scalar-pipe s_loads.
__global__ void __launch_bounds__(1024, 4) density_kernel(
    const float* __restrict__ z, const float* __restrict__ z0,
    const float* __restrict__ beta, const float* __restrict__ ws,
    float* __restrict__ out, int N) {
    __shared__ float tile[64 * 17];
    const int tid = threadIdx.x;
    const int lane = tid & 63;
    const int c = __builtin_amdgcn_readfirstlane(tid >> 6);
    const int s = blockIdx.x * 64 + lane;
    const int sl = s < N ? s : N - 1;    // clamp; only final store is guarded

    v2f zc2[8];
    {
        const float4* zp = (const float4*)(z + (size_t)sl * DIM);
        float4 a0 = zp[0], a1 = zp[1], a2 = zp[2], a3 = zp[3];
        zc2[0] = (v2f){a0.x, a0.y}; zc2[1] = (v2f){a0.z, a0.w};
        zc2[2] = (v2f){a1.x, a1.y}; zc2[3] = (v2f){a1.z, a1.w};
        zc2[4] = (v2f){a2.x, a2.y}; zc2[5] = (v2f){a2.z, a2.w};
        zc2[6] = (v2f){a3.x, a3.y}; zc2[7] = (v2f){a3.z, a3.w};
    }

    float slj = 0.0f;
    #pragma unroll
    for (int l = 0; l < LAYERS; ++l) {
        const v2f* z0p = (const v2f*)(z0 + (l * NC + c) * DIM);  // uniform -> s_load
        v2f d2[8];
        v2f r2a = (v2f){0.0f, 0.0f}, r2b = (v2f){0.0f, 0.0f};
        #pragma unroll
        for (int k = 0; k < 8; ++k) {
            d2[k] = zc2[k] - z0p[k];
            if (k & 1) r2b = __builtin_elementwise_fma(d2[k], d2[k], r2b);
            else       r2a = __builtin_elementwise_fma(d2[k], d2[k], r2a);
        }
        v2f r2v = r2a + r2b;
        float r2 = r2v.x + r2v.y;
        float r = sqrtf(r2);
        float al = ws[WS_ALPHA + l * NC + c];          // uniform -> s_load
        float b  = beta[l * NC + c];                   // uniform -> s_load
        float h  = __builtin_amdgcn_rcpf(al + r);
        float bh = b * h;
        v2f bh2 = (v2f){bh, bh};
        #pragma unroll
        for (int k = 0; k < 8; ++k)
            zc2[k] = __builtin_elementwise_fma(bh2, d2[k], zc2[k]);
        float t2 = fmaf(-(b * r * h), h, bh);
        slj += 15.0f * __logf(1.0f + bh) + __logf(1.0f + t2);
    }

    // q = || Linv_c*zk - mu2_c ||^2, packed over j (zeros above diag let us
    // round odd row lengths up to a whole pair).
    const v2f* Li2 = (const v2f*)(ws + WS_LINV + c * 256);  // row i: Li2[i*8+jj]
    const float* m2 = ws + WS_MU2 + c * 16;
    float q = 0.0f;
    #pragma unroll
    for (int i = 0; i < DIM; ++i) {
        v2f acc2 = (v2f){0.0f, 0.0f};
        #pragma unroll
        for (int jj = 0; jj <= (i >> 1); ++jj)
            acc2 = __builtin_elementwise_fma(Li2[i * 8 + jj], zc2[jj], acc2);
        float acc = (acc2.x + acc2.y) - m2[i];
        q = fmaf(acc, acc, q);
    }

    float res = ws[WS_CST + c] + fmaf(-0.5f, q, slj);
    if (res != res) res = -INFINITY;     // NaN -> -inf (reference semantics)

    // Transpose through LDS so the global store is fully coalesced
    // (stride-17 rows: 2-way bank aliasing only, free on gfx950).
    tile[lane * 17 + c] = res;
    __syncthreads();
    const int srow = tid >> 4, col = tid & 15;
    const int gs = blockIdx.x * 64 + srow;
    if (gs < N) out[(size_t)gs * NC + col] = tile[srow * 17 + col];
}

extern "C" void kernel_launch(void* const* d_in, const int* in_sizes, int n_in,
                              void* d_out, int out_size, void* d_ws, size_t ws_size,
                              hipStream_t stream) {
    const float* z    = (const float*)d_in[0];
    const float* z0   = (const float*)d_in[1];
    const float* la   = (const float*)d_in[2];
    const float* beta = (const float*)d_in[3];
    const float* mean = (const float*)d_in[4];
    const float* cov  = (const float*)d_in[5];
    float* out = (float*)d_out;
    float* ws  = (float*)d_ws;
    const int N = in_sizes[0] / DIM;

    hipLaunchKernelGGL(prep_kernel, dim3(1), dim3(256), 0, stream, cov, la, mean, ws);
    const int nb = (N + 63) / 64;
    hipLaunchKernelGGL(density_kernel, dim3(nb), dim3(1024), 0, stream,
                       z, z0, beta, ws, out, N);
}

// Round 6
// 138.578 us; speedup vs baseline: 1.1861x; 1.0253x over previous
//
#include <hip/hip_runtime.h>
#include <math.h>

#define NC 16
#define DIM 16
#define LAYERS 6

typedef float v2f __attribute__((ext_vector_type(2)));

// ws layout (floats)
#define WS_LINV  0      // [NC][DIM][DIM] row-major, zeros above diag, 4096
#define WS_MU2   4096   // [NC][DIM] = Linv_c * mean_c, 256
#define WS_CST   4352   // [NC], 16
#define WS_ALPHA 4368   // [L][NC] = exp(log_alpha), 96
#define WS_TOT   4464

// One block per component, one wave per block. All barriers are 1-wave
// (cheap); the 136-op substitution chain runs once per component in
// parallel across 16 CUs instead of 16 chains inside one block.
__global__ void __launch_bounds__(64) prep_kernel(
    const float* __restrict__ cov, const float* __restrict__ log_alpha,
    const float* __restrict__ mean, float* __restrict__ ws) {
    __shared__ float A[DIM * 17];     // padded: A[i][j] at i*17+j
    __shared__ float B[DIM * DIM];    // Linv staged for mu2 matvec
    const int c = blockIdx.x;
    const int t = threadIdx.x;        // 0..63
    for (int k = t; k < DIM * DIM; k += 64) {
        int r = k >> 4, j = k & 15;
        A[r * 17 + j] = cov[c * 256 + k];
    }
    __syncthreads();
    const int i = t & 15;
    const bool act = t < 16;
    // Parallel right-looking Cholesky: lane i owns row i.
    for (int k = 0; k < DIM; ++k) {
        if (act && i == k) A[k * 17 + k] = sqrtf(A[k * 17 + k]);
        __syncthreads();
        if (act && i > k) A[i * 17 + k] /= A[k * 17 + k];
        __syncthreads();
        if (act && i > k) {
            float lik = A[i * 17 + k];
            for (int j2 = k + 1; j2 <= i; ++j2)
                A[i * 17 + j2] -= lik * A[j2 * 17 + k];
        }
        __syncthreads();
    }
    // Forward substitution for column j of Linv — fully unrolled so x[]
    // stays in VGPRs. Lanes 16..63 compute duplicates, write nothing.
    const int j = i;
    float x[DIM];
    #pragma unroll
    for (int r = 0; r < DIM; ++r) {
        float s = (r == j) ? 1.0f : 0.0f;   // rows above j stay exactly 0
        #pragma unroll
        for (int k = 0; k < r; ++k) s = fmaf(-A[r * 17 + k], x[k], s);
        x[r] = s / A[r * 17 + r];
    }
    if (act) {
        #pragma unroll
        for (int r = 0; r < DIM; ++r) {
            B[r * 16 + j] = x[r];
            ws[WS_LINV + c * 256 + r * 16 + j] = x[r];   // 0 above diag
        }
    }
    __syncthreads();
    if (t == 0) {
        float hld = 0.0f;
        #pragma unroll
        for (int r = 0; r < DIM; ++r) hld += __logf(A[r * 17 + r]);
        const float log2pi = 1.8378770664093453f;
        ws[WS_CST + c] = -0.5f * (float)DIM * log2pi - hld;
    }
    if (t < LAYERS) ws[WS_ALPHA + t * NC + c] = __expf(log_alpha[t * NC + c]);
    if (act) {
        float m2 = 0.0f;
        #pragma unroll
        for (int jj = 0; jj < DIM; ++jj)
            m2 = fmaf(B[i * 16 + jj], mean[c * DIM + jj], m2);
        ws[WS_MU2 + c * 16 + i] = m2;
    }
}

// Packed-fp32 (VOP3P v_pk_*) version — UNCHANGED from Round 5 to isolate
// the prep change. Params read via wave-uniform addresses -> s_loads.
__global__ void __launch_bounds__(1024, 4) density_kernel(
    const float* __restrict__ z, const float* __restrict__ z0,
    const float* __restrict__ beta, const float* __restrict__ ws,
    float* __restrict__ out, int N) {
    __shared__ float tile[64 * 17];
    const int tid = threadIdx.x;
    const int lane = tid & 63;
    const int c = __builtin_amdgcn_readfirstlane(tid >> 6);
    const int s = blockIdx.x * 64 + lane;
    const int sl = s < N ? s : N - 1;    // clamp; only final store is guarded

    v2f zc2[8];
    {
        const float4* zp = (const float4*)(z + (size_t)sl * DIM);
        float4 a0 = zp[0], a1 = zp[1], a2 = zp[2], a3 = zp[3];
        zc2[0] = (v2f){a0.x, a0.y}; zc2[1] = (v2f){a0.z, a0.w};
        zc2[2] = (v2f){a1.x, a1.y}; zc2[3] = (v2f){a1.z, a1.w};
        zc2[4] = (v2f){a2.x, a2.y}; zc2[5] = (v2f){a2.z, a2.w};
        zc2[6] = (v2f){a3.x, a3.y}; zc2[7] = (v2f){a3.z, a3.w};
    }

    float slj = 0.0f;
    #pragma unroll
    for (int l = 0; l < LAYERS; ++l) {
        const v2f* z0p = (const v2f*)(z0 + (l * NC + c) * DIM);  // uniform -> s_load
        v2f d2[8];
        v2f r2a = (v2f){0.0f, 0.0f}, r2b = (v2f){0.0f, 0.0f};
        #pragma unroll
        for (int k = 0; k < 8; ++k) {
            d2[k] = zc2[k] - z0p[k];
            if (k & 1) r2b = __builtin_elementwise_fma(d2[k], d2[k], r2b);
            else       r2a = __builtin_elementwise_fma(d2[k], d2[k], r2a);
        }
        v2f r2v = r2a + r2b;
        float r2 = r2v.x + r2v.y;
        float r = sqrtf(r2);
        float al = ws[WS_ALPHA + l * NC + c];          // uniform -> s_load
        float b  = beta[l * NC + c];                   // uniform -> s_load
        float h  = __builtin_amdgcn_rcpf(al + r);
        float bh = b * h;
        v2f bh2 = (v2f){bh, bh};
        #pragma unroll
        for (int k = 0; k < 8; ++k)
            zc2[k] = __builtin_elementwise_fma(bh2, d2[k], zc2[k]);
        float t2 = fmaf(-(b * r * h), h, bh);
        slj += 15.0f * __logf(1.0f + bh) + __logf(1.0f + t2);
    }

    // q = || Linv_c*zk - mu2_c ||^2, packed over j (zeros above diag let us
    // round odd row lengths up to a whole pair).
    const v2f* Li2 = (const v2f*)(ws + WS_LINV + c * 256);  // row i: Li2[i*8+jj]
    const float* m2 = ws + WS_MU2 + c * 16;
    float q = 0.0f;
    #pragma unroll
    for (int i = 0; i < DIM; ++i) {
        v2f acc2 = (v2f){0.0f, 0.0f};
        #pragma unroll
        for (int jj = 0; jj <= (i >> 1); ++jj)
            acc2 = __builtin_elementwise_fma(Li2[i * 8 + jj], zc2[jj], acc2);
        float acc = (acc2.x + acc2.y) - m2[i];
        q = fmaf(acc, acc, q);
    }

    float res = ws[WS_CST + c] + fmaf(-0.5f, q, slj);
    if (res != res) res = -INFINITY;     // NaN -> -inf (reference semantics)

    // Transpose through LDS so the global store is fully coalesced
    // (stride-17 rows: 2-way bank aliasing only, free on gfx950).
    tile[lane * 17 + c] = res;
    __syncthreads();
    const int srow = tid >> 4, col = tid & 15;
    const int gs = blockIdx.x * 64 + srow;
    if (gs < N) out[(size_t)gs * NC + col] = tile[srow * 17 + col];
}

extern "C" void kernel_launch(void* const* d_in, const int* in_sizes, int n_in,
                              void* d_out, int out_size, void* d_ws, size_t ws_size,
                              hipStream_t stream) {
    const float* z    = (const float*)d_in[0];
    const float* z0   = (const float*)d_in[1];
    const float* la   = (const float*)d_in[2];
    const float* beta = (const float*)d_in[3];
    const float* mean = (const float*)d_in[4];
    const float* cov  = (const float*)d_in[5];
    float* out = (float*)d_out;
    float* ws  = (float*)d_ws;
    const int N = in_sizes[0] / DIM;

    hipLaunchKernelGGL(prep_kernel, dim3(NC), dim3(64), 0, stream, cov, la, mean, ws);
    const int nb = (N + 63) / 64;
    hipLaunchKernelGGL(density_kernel, dim3(nb), dim3(1024), 0, stream,
                       z, z0, beta, ws, out, N);
}